// Round 10
// baseline (41.382 us; speedup 1.0000x reference)
//
#include <hip/hip_runtime.h>
#include <math.h>

#define NQ 4
#define DIN 256
#define DOUT 64
#define NLAYER 2
#define TPB 256
#define PF 3                 // prefetch depth (iterations ahead)
#define K1_NIT 8             // 8 iters x 2 rows = 16 rows per wave

typedef float nt4 __attribute__((ext_vector_type(4)));

__device__ __forceinline__ float tanh_fast(float y) {
    float e = __expf(2.0f * y);
    return 1.0f - 2.0f / (e + 1.0f);
}

// ---------------- K1: f = pi*tanh(x@W1^T+b1) — pure NT read stream ----------
// 16 rows/wave, 64 rows/block, grid = B/64 = 2048 (8 blocks/CU, 2 rounds)
__global__ __launch_bounds__(TPB, 4) void qp_k1(
    const float* __restrict__ x, const float* __restrict__ W1,
    const float* __restrict__ b1, float* __restrict__ fbuf, int fstride)
{
    const int t = threadIdx.x;
    const int wave = t >> 6, lane = t & 63;
    const int half = lane >> 5;          // row parity within iteration
    const int cl   = lane & 31;          // float4 chunk within row half
    const int qsel = lane & 3;

    float4 w[4][2];
    #pragma unroll
    for (int q = 0; q < 4; ++q) {
        w[q][0] = ((const float4*)W1)[q*64 + cl];
        w[q][1] = ((const float4*)W1)[q*64 + 32 + cl];
    }
    const float4 bv = *(const float4*)b1;
    const float bsel = (qsel==0)?bv.x:(qsel==1)?bv.y:(qsel==2)?bv.z:bv.w;

    const int wrow = blockIdx.x * 64 + wave * 16;
    const int row0 = wrow + half;        // + it*2

    nt4 buf[PF+1][2];                    // ring, statically indexed
    #pragma unroll
    for (int k = 0; k < PF; ++k) {
        const nt4* xn = (const nt4*)(x + (size_t)(row0 + k*2) * DIN);
        buf[k][0] = __builtin_nontemporal_load(xn + cl);
        buf[k][1] = __builtin_nontemporal_load(xn + 32 + cl);
    }

    #pragma unroll
    for (int it = 0; it < K1_NIT; ++it) {
        if (it + PF < K1_NIT) {
            const nt4* xn = (const nt4*)(x + (size_t)(row0 + (it+PF)*2) * DIN);
            buf[(it+PF)&PF][0] = __builtin_nontemporal_load(xn + cl);
            buf[(it+PF)&PF][1] = __builtin_nontemporal_load(xn + 32 + cl);
        }
        const nt4 xv0 = buf[it&PF][0];
        const nt4 xv1 = buf[it&PF][1];

        float a0, a1, a2, a3;
        a0 = fmaf(xv0.x,w[0][0].x, fmaf(xv0.y,w[0][0].y, fmaf(xv0.z,w[0][0].z, xv0.w*w[0][0].w)));
        a1 = fmaf(xv0.x,w[1][0].x, fmaf(xv0.y,w[1][0].y, fmaf(xv0.z,w[1][0].z, xv0.w*w[1][0].w)));
        a2 = fmaf(xv0.x,w[2][0].x, fmaf(xv0.y,w[2][0].y, fmaf(xv0.z,w[2][0].z, xv0.w*w[2][0].w)));
        a3 = fmaf(xv0.x,w[3][0].x, fmaf(xv0.y,w[3][0].y, fmaf(xv0.z,w[3][0].z, xv0.w*w[3][0].w)));
        a0 = fmaf(xv1.x,w[0][1].x, fmaf(xv1.y,w[0][1].y, fmaf(xv1.z,w[0][1].z, fmaf(xv1.w,w[0][1].w, a0))));
        a1 = fmaf(xv1.x,w[1][1].x, fmaf(xv1.y,w[1][1].y, fmaf(xv1.z,w[1][1].z, fmaf(xv1.w,w[1][1].w, a1))));
        a2 = fmaf(xv1.x,w[2][1].x, fmaf(xv1.y,w[2][1].y, fmaf(xv1.z,w[2][1].z, fmaf(xv1.w,w[2][1].w, a2))));
        a3 = fmaf(xv1.x,w[3][1].x, fmaf(xv1.y,w[3][1].y, fmaf(xv1.z,w[3][1].z, fmaf(xv1.w,w[3][1].w, a3))));

        a0 += __shfl_xor(a0, 1, 64);  a1 += __shfl_xor(a1, 1, 64);
        a2 += __shfl_xor(a2, 1, 64);  a3 += __shfl_xor(a3, 1, 64);
        a0 += __shfl_xor(a0, 2, 64);  a1 += __shfl_xor(a1, 2, 64);
        a2 += __shfl_xor(a2, 2, 64);  a3 += __shfl_xor(a3, 2, 64);
        float v = (qsel==0)?a0:(qsel==1)?a1:(qsel==2)?a2:a3;
        v += __shfl_xor(v, 4, 64);
        v += __shfl_xor(v, 8, 64);
        v += __shfl_xor(v, 16, 64);

        if (cl < 4) {
            const float PI = 3.14159265358979f;
            fbuf[(size_t)(row0 + it*2) * fstride + qsel] = PI * tanh_fast(v + bsel);
        }
    }
}

// ---------------- K2: circuit + out = q@W2^T + b2 — write-bound -------------
// 1 row/thread, 256 rows/block, grid = B/256 = 512
__global__ __launch_bounds__(TPB, 4) void qp_k2(
    const float* __restrict__ fbuf, int fstride,
    const float* __restrict__ wts, const float* __restrict__ W2,
    const float* __restrict__ b2, float* __restrict__ out)
{
    __shared__ __align__(16) float qs[TPB][NQ];
    __shared__ __align__(16) float us[8][8];

    const int t = threadIdx.x;
    const int brow = blockIdx.x * TPB;

    if (t < 8) {
        const float phi = wts[t*3 + 0], th = wts[t*3 + 1], om = wts[t*3 + 2];
        float sth, cth; sincosf(0.5f*th, &sth, &cth);
        float sp, cp;   sincosf(0.5f*(phi+om), &sp, &cp);
        float sm, cm;   sincosf(0.5f*(phi-om), &sm, &cm);
        us[t][0] =  cth*cp; us[t][1] = -cth*sp;
        us[t][2] = -sth*cm; us[t][3] = -sth*sm;
        us[t][4] =  sth*cm; us[t][5] = -sth*sm;
        us[t][6] =  cth*cp; us[t][7] =  cth*sp;
    }
    __syncthreads();

    {
        const float4 fv = *(const float4*)(fbuf + (size_t)(brow + t) * fstride);
        const float fq[4] = {fv.x, fv.y, fv.z, fv.w};
        const float IS2 = 0.70710678118654752f;
        float vr[4][2], vi[4][2];
        #pragma unroll
        for (int i = 0; i < 4; ++i) {
            const float fi = fq[i];
            const float f2 = fi*fi;
            const float ca = rsqrtf(1.0f + f2);
            const float ch = sqrtf(0.5f*(1.0f + ca));
            const float sh = copysignf(sqrtf(fmaxf(0.5f*(1.0f - ca), 0.0f)), fi);
            const float cb = rsqrtf(1.0f + f2*f2);
            const float cbh = sqrtf(0.5f*(1.0f + cb));
            const float sbh = sqrtf(fmaxf(0.5f*(1.0f - cb), 0.0f));
            const float u0 = (ch - sh) * IS2;
            const float u1 = (ch + sh) * IS2;
            vr[i][0] = u0 * cbh;  vi[i][0] = -u0 * sbh;
            vr[i][1] = u1 * cbh;  vi[i][1] =  u1 * sbh;
        }
        float ar[16], ai[16];
        #pragma unroll
        for (int i0 = 0; i0 < 2; ++i0)
        #pragma unroll
        for (int i1 = 0; i1 < 2; ++i1) {
            const float pr  = vr[0][i0]*vr[1][i1] - vi[0][i0]*vi[1][i1];
            const float pim = vr[0][i0]*vi[1][i1] + vi[0][i0]*vr[1][i1];
            #pragma unroll
            for (int i2 = 0; i2 < 2; ++i2)
            #pragma unroll
            for (int i3 = 0; i3 < 2; ++i3) {
                const float qr  = vr[2][i2]*vr[3][i3] - vi[2][i2]*vi[3][i3];
                const float qim = vr[2][i2]*vi[3][i3] + vi[2][i2]*vr[3][i3];
                const int idx = i0*8 + i1*4 + i2*2 + i3;
                ar[idx] = pr*qr - pim*qim;
                ai[idx] = pr*qim + pim*qr;
            }
        }
        #pragma unroll
        for (int l = 0; l < NLAYER; ++l) {
            constexpr int cpairs[8][2] = {{0,1},{1,2},{2,3},{3,0},{0,2},{1,3},{2,0},{3,1}};
            #pragma unroll
            for (int g = 0; g < 8; ++g) {
                const int bc = 8 >> cpairs[g][0];
                const int bt = 8 >> cpairs[g][1];
                #pragma unroll
                for (int m = 0; m < 16; ++m) {
                    if ((m & bc) && !(m & bt)) {
                        const int m2 = m | bt;
                        float tr = ar[m]; ar[m] = ar[m2]; ar[m2] = tr;
                        float ti = ai[m]; ai[m] = ai[m2]; ai[m2] = ti;
                    }
                }
            }
            #pragma unroll
            for (int i = 0; i < 4; ++i) {
                const float* u = &us[l*4 + i][0];
                const float u00r=u[0], u00i=u[1], u01r=u[2], u01i=u[3];
                const float u10r=u[4], u10i=u[5], u11r=u[6], u11i=u[7];
                const int bq = 8 >> i;
                #pragma unroll
                for (int m = 0; m < 16; ++m) {
                    if (!(m & bq)) {
                        const int m2 = m | bq;
                        const float a0r=ar[m], a0i=ai[m], a1r=ar[m2], a1i=ai[m2];
                        ar[m]  = u00r*a0r - u00i*a0i + u01r*a1r - u01i*a1i;
                        ai[m]  = u00r*a0i + u00i*a0r + u01r*a1i + u01i*a1r;
                        ar[m2] = u10r*a0r - u10i*a0i + u11r*a1r - u11i*a1i;
                        ai[m2] = u10r*a0i + u10i*a0r + u11r*a1i + u11i*a1r;
                    }
                }
            }
        }
        float z0=0.f, z1=0.f, z2=0.f, z3=0.f;
        #pragma unroll
        for (int m = 0; m < 16; ++m) {
            const float p = ar[m]*ar[m] + ai[m]*ai[m];
            z0 += (m & 8) ? -p : p;
            z1 += (m & 4) ? -p : p;
            z2 += (m & 2) ? -p : p;
            z3 += (m & 1) ? -p : p;
        }
        float4 qv; qv.x=z0; qv.y=z1; qv.z=z2; qv.w=z3;
        ((float4*)qs)[t] = qv;
    }
    __syncthreads();

    // projection epilogue: coalesced NT float4 stores
    {
        const int j4 = t & 15;
        const int rb = t >> 4;           // 0..15
        float4 w2r[4];
        #pragma unroll
        for (int jj = 0; jj < 4; ++jj) w2r[jj] = ((const float4*)W2)[j4*4 + jj];
        const float4 b2v = ((const float4*)b2)[j4];

        #pragma unroll
        for (int e = 0; e < TPB/16; ++e) {
            const int r = e*16 + rb;
            const float4 q = ((const float4*)qs)[r];
            nt4 o;
            o.x = fmaf(q.x,w2r[0].x, fmaf(q.y,w2r[0].y, fmaf(q.z,w2r[0].z, fmaf(q.w,w2r[0].w, b2v.x))));
            o.y = fmaf(q.x,w2r[1].x, fmaf(q.y,w2r[1].y, fmaf(q.z,w2r[1].z, fmaf(q.w,w2r[1].w, b2v.y))));
            o.z = fmaf(q.x,w2r[2].x, fmaf(q.y,w2r[2].y, fmaf(q.z,w2r[2].z, fmaf(q.w,w2r[2].w, b2v.z))));
            o.w = fmaf(q.x,w2r[3].x, fmaf(q.y,w2r[3].y, fmaf(q.z,w2r[3].z, fmaf(q.w,w2r[3].w, b2v.w))));
            __builtin_nontemporal_store(o, (nt4*)(out + (size_t)(brow + r) * DOUT) + j4);
        }
    }
}

extern "C" void kernel_launch(void* const* d_in, const int* in_sizes, int n_in,
                              void* d_out, int out_size, void* d_ws, size_t ws_size,
                              hipStream_t stream) {
    const float* x  = (const float*)d_in[0];
    const float* W1 = (const float*)d_in[1];
    const float* b1 = (const float*)d_in[2];
    const float* wt = (const float*)d_in[3];
    const float* W2 = (const float*)d_in[4];
    const float* b2 = (const float*)d_in[5];
    float* out = (float*)d_out;
    const int B = in_sizes[0] / DIN;        // 131072

    float* fbuf;
    int fstride;
    if (ws_size >= (size_t)B * NQ * sizeof(float)) {
        fbuf = (float*)d_ws; fstride = NQ;     // contiguous 2 MB, L2-resident
    } else {
        fbuf = out; fstride = DOUT;            // fallback: row-embedded in out
    }

    qp_k1<<<B / 64, TPB, 0, stream>>>(x, W1, b1, fbuf, fstride);
    qp_k2<<<B / TPB, TPB, 0, stream>>>(fbuf, fstride, wt, W2, b2, out);
}